// Round 13
// baseline (247.097 us; speedup 1.0000x reference)
//
#include <hip/hip_runtime.h>
#include <cstdint>

typedef unsigned short u16;
typedef uint32_t u32;
typedef __attribute__((ext_vector_type(8))) short bf16x8;
typedef __attribute__((ext_vector_type(4))) float f32x4;
typedef __attribute__((ext_vector_type(16))) float f32x16;

#define NB 4
#define NT 2048
#define NC 1024
#define NH 16
#define ND 64
#define NM (NB*NT)      // 8192
#define N3C (3*NC)      // 3072

// Q scale: 1/sqrt(64) * log2(e)  (softmax runs in log2 domain -> exp2)
#define QSCALE 0.18033688011112042f

static __device__ __forceinline__ u16 f2bf(float f){
  union { float f; uint32_t u; } v; v.f = f;
  return (u16)((v.u + 0x7fffu + ((v.u >> 16) & 1u)) >> 16);
}

// async 16B global->LDS (LDS dest is wave-uniform base + lane*16)
static __device__ __forceinline__ void gld_lds16(void* lds, const void* g){
  auto lp = reinterpret_cast<__attribute__((address_space(3))) uint32_t*>(
      reinterpret_cast<uintptr_t>(lds));
  auto gp = reinterpret_cast<__attribute__((address_space(1))) uint32_t*>(
      reinterpret_cast<uintptr_t>(g));
  __builtin_amdgcn_global_load_lds(gp, lp, 16, 0, 0);
}

static __device__ __forceinline__ f32x16 mfma32(bf16x8 a, bf16x8 b, f32x16 c){
  return __builtin_amdgcn_mfma_f32_32x32x16_bf16(a, b, c, 0, 0, 0);
}

// ---------------- elementwise cast fp32 -> bf16 ----------------
__global__ __launch_bounds__(256) void k_cast(const float* __restrict__ in,
                                              u16* __restrict__ out){
  const int i = (blockIdx.x * 256 + threadIdx.x) * 4;
  const float4 vv = *reinterpret_cast<const float4*>(in + i);
  union { u16 s[4]; uint64_t u; } pk;
  pk.s[0] = f2bf(vv.x); pk.s[1] = f2bf(vv.y);
  pk.s[2] = f2bf(vv.z); pk.s[3] = f2bf(vv.w);
  *reinterpret_cast<uint64_t*>(out + i) = pk.u;
}

// ---------------- tiled transpose + cast: in[R][Cc] fp32 -> out[Cc][R] bf16 ----------------
__global__ __launch_bounds__(256) void k_transpose_cast(const float* __restrict__ in,
                                                        u16* __restrict__ out,
                                                        int R, int Cc){
  __shared__ float tile[32][33];
  const int bx = blockIdx.x * 32, by = blockIdx.y * 32;
  const int tx = threadIdx.x, ty = threadIdx.y;
#pragma unroll
  for (int i = 0; i < 32; i += 8)
    tile[ty + i][tx] = in[(size_t)(by + ty + i) * Cc + bx + tx];
  __syncthreads();
#pragma unroll
  for (int i = 0; i < 32; i += 8)
    out[(size_t)(bx + ty + i) * R + by + tx] = f2bf(tile[tx][ty + i]);
}

// ---------------- shared GEMM main loop: C[128x128] tile, A[M][K] * Bt[N][K]^T ----------------
static __device__ __forceinline__ void gemm_mainloop(
    const u16* __restrict__ A, const u16* __restrict__ Bt, int K,
    int m0, int n0, u16* As, u16* Bs, f32x4 acc[4][4])
{
  const int tid = threadIdx.x;
  const int wave = tid >> 6, lane = tid & 63;
  const int wm = wave >> 1, wn = wave & 1;
  const int o0 = tid * 8, o1 = o0 + 2048;           // elem offsets in the 128x32 tile
  const u16* Ag0 = A  + (size_t)(m0 + (o0 >> 5)) * K + (o0 & 31);
  const u16* Ag1 = A  + (size_t)(m0 + (o1 >> 5)) * K + (o1 & 31);
  const u16* Bg0 = Bt + (size_t)(n0 + (o0 >> 5)) * K + (o0 & 31);
  const u16* Bg1 = Bt + (size_t)(n0 + (o1 >> 5)) * K + (o1 & 31);
  u16* AsW = As + wave * 512;   // wave-uniform LDS base (1024 B per wave)
  u16* BsW = Bs + wave * 512;
  const int kb = (lane >> 4) * 8, rl = lane & 15;

  for (int kt = 0; kt < K; kt += 32){
    gld_lds16(AsW,        Ag0 + kt);
    gld_lds16(AsW + 2048, Ag1 + kt);
    gld_lds16(BsW,        Bg0 + kt);
    gld_lds16(BsW + 2048, Bg1 + kt);
    __syncthreads();
    bf16x8 af[4], bfr[4];
#pragma unroll
    for (int i = 0; i < 4; i++){
      af[i]  = *reinterpret_cast<const bf16x8*>(&As[(wm * 64 + i * 16 + rl) * 32 + kb]);
      bfr[i] = *reinterpret_cast<const bf16x8*>(&Bs[(wn * 64 + i * 16 + rl) * 32 + kb]);
    }
#pragma unroll
    for (int i = 0; i < 4; i++)
#pragma unroll
      for (int j = 0; j < 4; j++)
        acc[i][j] = __builtin_amdgcn_mfma_f32_16x16x32_bf16(af[i], bfr[j], acc[i][j], 0, 0, 0);
    __syncthreads();
  }
}

// ---------------- GEMM 1: x @ w_qkv + b_qkv -> Q (scaled), K (swizzled), V (transposed+swizzled) ----------------
// Q: [b,h,t,d] standard, values * QSCALE
// K: per (b,h): tile kt (4096 elems): (t&63)*64 + (d ^ ((t&7)<<3))         [16B-chunk swizzle]
// V: per (b,h): tile kt (4096 elems): d*64 + ((((t>>3)&7)^(d&7))<<3)+(t&7) [transposed, 16B-chunk swizzle]
__global__ __launch_bounds__(256) void k_gemm_qkv(
    const u16* __restrict__ A, const u16* __restrict__ Bt,
    const float* __restrict__ bias,
    u16* __restrict__ qo, u16* __restrict__ ko, u16* __restrict__ vo)
{
  __shared__ u16 As[128 * 32], Bs[128 * 32];
  f32x4 acc[4][4] = {};
  const int m0 = blockIdx.y * 128, n0 = blockIdx.x * 128;
  gemm_mainloop(A, Bt, NC, m0, n0, As, Bs, acc);

  const int tid = threadIdx.x;
  const int wave = tid >> 6, lane = tid & 63;
  const int wm = wave >> 1, wn = wave & 1;
  const int rl = lane & 15, rg = lane >> 4;
  const int which = n0 >> 10;   // uniform per block: 0=Q 1=K 2=V
  if (which == 2){
    // V: pack 4 consecutive t (r=0..3, t&3=r) into one 8B store
#pragma unroll
    for (int j = 0; j < 4; j++){
      const int n = n0 + wn * 64 + j * 16 + rl;
      const int cc = n & 1023;
      const int h = cc >> 6, d = cc & 63;
      const float bb = bias[n];
#pragma unroll
      for (int i = 0; i < 4; i++){
        const int mb = m0 + wm * 64 + i * 16 + rg * 4;
        const int b = mb >> 11, t0 = mb & 2047;
        const size_t bhb = ((size_t)(b * NH + h)) * NT * ND;
        union { u16 s[4]; uint64_t u; } pk4;
#pragma unroll
        for (int r = 0; r < 4; r++) pk4.s[r] = f2bf(acc[i][j][r] + bb);
        *reinterpret_cast<uint64_t*>(
          &vo[bhb + (size_t)(t0 >> 6) * 4096 + d * 64 +
              ((((t0 >> 3) & 7) ^ (d & 7)) << 3) + (t0 & 7)]) = pk4.u;
      }
    }
  } else {
#pragma unroll
    for (int j = 0; j < 4; j++){
      const int n = n0 + wn * 64 + j * 16 + rl;
      const int cc = n & 1023;
      const int h = cc >> 6, d = cc & 63;
      const float bb = bias[n];
#pragma unroll
      for (int i = 0; i < 4; i++){
#pragma unroll
        for (int r = 0; r < 4; r++){
          const int m = m0 + wm * 64 + i * 16 + rg * 4 + r;
          const int b = m >> 11, t = m & 2047;
          const size_t bhb = ((size_t)(b * NH + h)) * NT * ND;
          const float val = acc[i][j][r] + bb;
          if (which == 0){
            qo[bhb + (size_t)t * ND + d] = f2bf(val * QSCALE);
          } else {
            ko[bhb + (size_t)(t >> 6) * 4096 + (t & 63) * 64 + (d ^ ((t & 7) << 3))] = f2bf(val);
          }
        }
      }
    }
  }
}

// ---------------- GEMM 2: attn_out @ w_proj + b_proj -> fp32 out ----------------
__global__ __launch_bounds__(256) void k_gemm_proj(
    const u16* __restrict__ A, const u16* __restrict__ Bt,
    const float* __restrict__ bias, float* __restrict__ out)
{
  __shared__ u16 As[128 * 32], Bs[128 * 32];
  f32x4 acc[4][4] = {};
  const int m0 = blockIdx.y * 128, n0 = blockIdx.x * 128;
  gemm_mainloop(A, Bt, NC, m0, n0, As, Bs, acc);

  const int tid = threadIdx.x;
  const int wave = tid >> 6, lane = tid & 63;
  const int wm = wave >> 1, wn = wave & 1;
  const int rl = lane & 15, rg = lane >> 4;
#pragma unroll
  for (int i = 0; i < 4; i++){
#pragma unroll
    for (int r = 0; r < 4; r++){
      const int m = m0 + wm * 64 + i * 16 + rg * 4 + r;
#pragma unroll
      for (int j = 0; j < 4; j++){
        const int n = n0 + wn * 64 + j * 16 + rl;
        out[(size_t)m * NC + n] = acc[i][j][r] + bias[n];
      }
    }
  }
}

// ---------------- flash 32x32 update: one 64-k tile against 32 q-rows/wave ----------------
// S^T[k][q] via mfma32(K,Q): C col=lane&31=q, row k=(r&3)+8*(r>>2)+4*hi (+32 for s1).
// Softmax fully lane-local in q; P B-frags built via cvt_pk + permlane32_swap (T12).
static __device__ __forceinline__ void upd32(
    const u16* __restrict__ Kc, const u16* __restrict__ Vc,
    const bf16x8* qf, f32x16& o0, f32x16& o1,
    float& mrun, float& lrun, int kbase, int qglob, bool domask,
    int hi, int l31, int l7)
{
  f32x16 s0 = {}, s1 = {};
  __builtin_amdgcn_s_setprio(1);
#pragma unroll
  for (int ds = 0; ds < 4; ds++){
    const int sw = ((ds * 2 + hi) ^ l7) << 3;
    const bf16x8 kf0 = *reinterpret_cast<const bf16x8*>(&Kc[l31 * 64 + sw]);
    const bf16x8 kf1 = *reinterpret_cast<const bf16x8*>(&Kc[(32 + l31) * 64 + sw]);
    s0 = mfma32(kf0, qf[ds], s0);
    s1 = mfma32(kf1, qf[ds], s1);
  }
  __builtin_amdgcn_s_setprio(0);

  if (domask){
#pragma unroll
    for (int r = 0; r < 16; r++){
      const int krow = (r & 3) + 8 * (r >> 2) + 4 * hi;
      if (kbase + krow      > qglob) s0[r] = -3e38f;
      if (kbase + 32 + krow > qglob) s1[r] = -3e38f;
    }
  }

  // tree max over the lane's 32 k-values, then one cross-half shfl
  float ta[8];
#pragma unroll
  for (int i = 0; i < 8; i++)
    ta[i] = fmaxf(fmaxf(s0[2*i], s0[2*i+1]), fmaxf(s1[2*i], s1[2*i+1]));
  float rmax = fmaxf(fmaxf(fmaxf(ta[0], ta[1]), fmaxf(ta[2], ta[3])),
                     fmaxf(fmaxf(ta[4], ta[5]), fmaxf(ta[6], ta[7])));
  rmax = fmaxf(rmax, __shfl_xor(rmax, 32));

  // defer-max: rescale only when the row max grew by >8 (P bounded by 2^8).
  // alpha is already per-lane in q (O^T cols = lane&31) -> no broadcast.
  if (!__all(rmax <= mrun + 8.0f)){
    const float mnew = fmaxf(mrun, rmax);
    const float alpha = exp2f(mrun - mnew);
    mrun = mnew;
    lrun *= alpha;
    o0 *= alpha;
    o1 *= alpha;
  }
#pragma unroll
  for (int r = 0; r < 16; r++){
    s0[r] = exp2f(s0[r] - mrun);
    s1[r] = exp2f(s1[r] - mrun);
  }
  float sa[8];
#pragma unroll
  for (int i = 0; i < 8; i++)
    sa[i] = (s0[2*i] + s0[2*i+1]) + (s1[2*i] + s1[2*i+1]);
  float rs = ((sa[0] + sa[1]) + (sa[2] + sa[3])) + ((sa[4] + sa[5]) + (sa[6] + sa[7]));
  rs += __shfl_xor(rs, 32);
  lrun += rs;

  // PV: per k-slot ks (16 k's), build P B-frag (lane=col q, k'=hi*8+j) from the
  // S^T C-frag via 4 cvt_pk + 2 permlane32_swap, then 2 MFMAs (d=0..31, 32..63).
  // permlane32_swap(vdst,vsrc): vdst[32:63] <-> vsrc[0:31].
  //   wa={lo:(k0,k1),hi:(k4,k5)}, wc={lo:(k8,k9),hi:(k12,k13)}
  //   swap(wa,wc) -> wa={lo:(k0,k1),hi:(k8,k9)}=word0, wc={lo:(k4,k5),hi:(k12,k13)}=word2
#pragma unroll
  for (int ks = 0; ks < 4; ks++){
    u32 wa, wb, wc, wd;
    if (ks < 2){
      const int rb = ks * 8;
      asm("v_cvt_pk_bf16_f32 %0, %1, %2" : "=v"(wa) : "v"(s0[rb+0]), "v"(s0[rb+1]));
      asm("v_cvt_pk_bf16_f32 %0, %1, %2" : "=v"(wb) : "v"(s0[rb+2]), "v"(s0[rb+3]));
      asm("v_cvt_pk_bf16_f32 %0, %1, %2" : "=v"(wc) : "v"(s0[rb+4]), "v"(s0[rb+5]));
      asm("v_cvt_pk_bf16_f32 %0, %1, %2" : "=v"(wd) : "v"(s0[rb+6]), "v"(s0[rb+7]));
    } else {
      const int rb = (ks - 2) * 8;
      asm("v_cvt_pk_bf16_f32 %0, %1, %2" : "=v"(wa) : "v"(s1[rb+0]), "v"(s1[rb+1]));
      asm("v_cvt_pk_bf16_f32 %0, %1, %2" : "=v"(wb) : "v"(s1[rb+2]), "v"(s1[rb+3]));
      asm("v_cvt_pk_bf16_f32 %0, %1, %2" : "=v"(wc) : "v"(s1[rb+4]), "v"(s1[rb+5]));
      asm("v_cvt_pk_bf16_f32 %0, %1, %2" : "=v"(wd) : "v"(s1[rb+6]), "v"(s1[rb+7]));
    }
    asm("v_permlane32_swap_b32 %0, %1" : "+v"(wa), "+v"(wc));
    asm("v_permlane32_swap_b32 %0, %1" : "+v"(wb), "+v"(wd));
    union { u32 u[4]; bf16x8 v; } pf;
    pf.u[0] = wa; pf.u[1] = wb; pf.u[2] = wc; pf.u[3] = wd;
    const int sw = ((ks * 2 + hi) ^ l7) << 3;
    const bf16x8 vf0 = *reinterpret_cast<const bf16x8*>(&Vc[l31 * 64 + sw]);
    const bf16x8 vf1 = *reinterpret_cast<const bf16x8*>(&Vc[(32 + l31) * 64 + sw]);
    __builtin_amdgcn_s_setprio(1);
    o0 = mfma32(vf0, pf.v, o0);
    o1 = mfma32(vf1, pf.v, o1);
    __builtin_amdgcn_s_setprio(0);
  }
}

// epilogue: O^T[d][q]/l -> ao row q, cols h*64+d (4 consecutive d per 8B store)
static __device__ __forceinline__ void epi32(u16* __restrict__ ao, size_t rowb,
                                             float li, const f32x16& oa,
                                             const f32x16& ob, int hi){
#pragma unroll
  for (int dsub = 0; dsub < 2; dsub++){
    const f32x16& ov = dsub ? ob : oa;
#pragma unroll
    for (int rg = 0; rg < 4; rg++){
      union { u16 s4[4]; uint64_t u; } pk4;
#pragma unroll
      for (int q4 = 0; q4 < 4; q4++) pk4.s4[q4] = f2bf(ov[rg * 4 + q4] * li);
      *reinterpret_cast<uint64_t*>(&ao[rowb + dsub * 32 + rg * 8 + hi * 4]) = pk4.u;
    }
  }
}

// ---------------- causal flash attention, 32x32 MFMA, merged dual q-block sweep ----------------
// Block px serves q-blocks {px, 15-px} (128 rows each; wave w owns 32 rows of each).
// One KV sweep 0..2*qb2+1; state1 rides along while t <= its causal limit.
// Round-9-proven sync skeleton: dbuf LDS, raw s_barrier, counted vmcnt(4).
__global__ __launch_bounds__(256) void k_flash(
    const u16* __restrict__ q, const u16* __restrict__ k,
    const u16* __restrict__ v, u16* __restrict__ ao)
{
  __shared__ u16 Ks[2][4096];   // [buf][(t&63)*64 + swz-d]  16B-chunk swizzle by (t&7)
  __shared__ u16 Vt[2][4096];   // [buf][d*64 + swz-k]       16B-chunk swizzle by (d&7)
  const int tid = threadIdx.x, wave = tid >> 6, lane = tid & 63;
  const int l31 = lane & 31, hi = lane >> 5, l7 = lane & 7;
  const int c0 = wave * 2;
  const int px = blockIdx.x, bh = blockIdx.y;
  const int qb1 = px, qb2 = 15 - px;
  const int npt = 2 * qb2 + 2;
  const int tmax1 = 2 * qb1 + (wave >> 1);
  const int tmax2 = 2 * qb2 + (wave >> 1);
  const size_t base = (size_t)bh * NT * ND;
  const u16* kg0 = k + base;
  const u16* vg0 = v + base;
  const int qg1 = qb1 * 128 + wave * 32 + l31;
  const int qg2 = qb2 * 128 + wave * 32 + l31;

  // Q B-frags: lane holds col q, k'=d = ds*16 + hi*8 + j (16B global loads)
  bf16x8 q1[4], q2[4];
  {
    const u16* p1 = q + base + (size_t)qg1 * 64 + hi * 8;
    const u16* p2 = q + base + (size_t)qg2 * 64 + hi * 8;
#pragma unroll
    for (int ds = 0; ds < 4; ds++){
      q1[ds] = *reinterpret_cast<const bf16x8*>(p1 + ds * 16);
      q2[ds] = *reinterpret_cast<const bf16x8*>(p2 + ds * 16);
    }
  }
  asm volatile("" : "+v"(q1[0]), "+v"(q1[1]), "+v"(q1[2]), "+v"(q1[3]),
                    "+v"(q2[0]), "+v"(q2[1]), "+v"(q2[2]), "+v"(q2[3]));

  f32x16 o1a = {}, o1b = {}, o2a = {}, o2b = {};
  float m1 = -1e30f, l1 = 0.f, m2 = -1e30f, l2 = 0.f;

#define STAGE(BUF, T)                                                          \
  {                                                                            \
    const u16* kg = kg0 + (size_t)(T) * 4096;                                  \
    const u16* vg = vg0 + (size_t)(T) * 4096;                                  \
    gld_lds16(&Ks[BUF][(c0    ) * 512], kg + (c0    ) * 512 + lane * 8);       \
    gld_lds16(&Ks[BUF][(c0 + 1) * 512], kg + (c0 + 1) * 512 + lane * 8);       \
    gld_lds16(&Vt[BUF][(c0    ) * 512], vg + (c0    ) * 512 + lane * 8);       \
    gld_lds16(&Vt[BUF][(c0 + 1) * 512], vg + (c0 + 1) * 512 + lane * 8);       \
  }

  // prologue: stage tile 0 -> buf 0
  STAGE(0, 0);

  for (int t = 0; t < npt; ++t){
    const int cur = t & 1, nxt = cur ^ 1;
    if (t + 1 < npt){
      STAGE(nxt, t + 1);
      asm volatile("s_waitcnt vmcnt(4)" ::: "memory");   // own tile-t loads done; t+1 in flight
    } else {
      asm volatile("s_waitcnt vmcnt(0)" ::: "memory");
    }
    __builtin_amdgcn_sched_barrier(0);
    __builtin_amdgcn_s_barrier();    // raw: no implicit vmcnt(0) drain

    const u16* Kc = Ks[cur];
    const u16* Vc = Vt[cur];
    if (t <= tmax2)
      upd32(Kc, Vc, q2, o2a, o2b, m2, l2, t * 64, qg2, t == tmax2, hi, l31, l7);
    if (t <= tmax1)
      upd32(Kc, Vc, q1, o1a, o1b, m1, l1, t * 64, qg1, t == tmax1, hi, l31, l7);

    asm volatile("s_waitcnt lgkmcnt(0)" ::: "memory");   // all LDS reads of buf[cur] sampled
    __builtin_amdgcn_sched_barrier(0);
    __builtin_amdgcn_s_barrier();    // release buf[cur] for stage(t+2)
  }
#undef STAGE

  const int b = bh >> 4, h = bh & 15;
  epi32(ao, ((size_t)b * NT + qg1) * NC + h * 64, 1.0f / l1, o1a, o1b, hi);
  epi32(ao, ((size_t)b * NT + qg2) * NC + h * 64, 1.0f / l2, o2a, o2b, hi);
}

extern "C" void kernel_launch(void* const* d_in, const int* in_sizes, int n_in,
                              void* d_out, int out_size, void* d_ws, size_t ws_size,
                              hipStream_t stream){
  const float* x      = (const float*)d_in[0];
  const float* w_qkv  = (const float*)d_in[1];
  const float* b_qkv  = (const float*)d_in[2];
  const float* w_proj = (const float*)d_in[3];
  const float* b_proj = (const float*)d_in[4];
  float* out = (float*)d_out;

  u16* ws = (u16*)d_ws;
  u16* xb     = ws;                 //  [B,T,C] bf16
  u16* qb     = ws + 8388608;       //  [B,H,T,D] standard
  u16* kb     = ws + 16777216;      //  [B,H] x tiles, swizzled
  u16* vb     = ws + 25165824;      //  [B,H] x tiles, transposed+swizzled
  u16* aob    = ws + 33554432;      //  [B,T,C]
  u16* wqkvT  = ws + 41943040;      //  [3C,C]
  u16* wprojT = ws + 45088768;      //  [C,C]

  k_cast<<<8388608 / 1024, 256, 0, stream>>>(x, xb);
  k_transpose_cast<<<dim3(N3C / 32, NC / 32), dim3(32, 8), 0, stream>>>(w_qkv, wqkvT, NC, N3C);
  k_transpose_cast<<<dim3(NC / 32, NC / 32), dim3(32, 8), 0, stream>>>(w_proj, wprojT, NC, NC);
  k_gemm_qkv<<<dim3(N3C / 128, NM / 128), 256, 0, stream>>>(xb, wqkvT, b_qkv, qb, kb, vb);
  k_flash<<<dim3(8, NB * NH), 256, 0, stream>>>(qb, kb, vb, aob);
  k_gemm_proj<<<dim3(NC / 128, NM / 128), 256, 0, stream>>>(aob, wprojT, b_proj, out);
}